// Round 8
// baseline (648.357 us; speedup 1.0000x reference)
//
#include <hip/hip_runtime.h>

typedef unsigned int u32;
typedef unsigned short u16;
typedef short s16x8 __attribute__((ext_vector_type(8)));
typedef float f32x4 __attribute__((ext_vector_type(4)));

// ---------- helpers ----------
__device__ __forceinline__ u16 f2bf(float f) {
  u32 u = __float_as_uint(f);
  u32 r = (u + 0x7fffu + ((u >> 16) & 1u)) >> 16;
  return (u16)r;
}

// async global->LDS, 16B per lane. LDS dest = wave-uniform base + lane*16.
__device__ __forceinline__ void g2l16(u16* lds, const u16* g) {
  __builtin_amdgcn_global_load_lds(
      (const __attribute__((address_space(1))) void*)g,
      (__attribute__((address_space(3))) void*)lds, 16, 0, 0);
}

// ---------- pass 1: per-row softmax over 16384 fp32 — SINGLE feat read.
__global__ __launch_bounds__(256) void row_softmax_bf16(
    const float* __restrict__ feat, u16* __restrict__ expx,
    u16* __restrict__ xbf) {
  const long long row = blockIdx.x;  // 0..2047
  const float* xp = feat + row * 16384;
  const int tid = threadIdx.x, wv = tid >> 6, ln = tid & 63;
  __shared__ float red[4];
  float4 v[16];
  float mx = -1e30f;
#pragma unroll
  for (int p = 0; p < 16; ++p) {
    v[p] = *(const float4*)(xp + tid * 4 + p * 1024);
    mx = fmaxf(mx, fmaxf(fmaxf(v[p].x, v[p].y), fmaxf(v[p].z, v[p].w)));
  }
  // bf16 copy of x (independent of stats) — store while regs are hot
  u16* bp = xbf + row * 16384;
#pragma unroll
  for (int p = 0; p < 16; ++p) {
    uint2 ow;
    ow.x = (u32)f2bf(v[p].x) | ((u32)f2bf(v[p].y) << 16);
    ow.y = (u32)f2bf(v[p].z) | ((u32)f2bf(v[p].w) << 16);
    *(uint2*)(bp + tid * 4 + p * 1024) = ow;
  }
  for (int o = 32; o; o >>= 1) mx = fmaxf(mx, __shfl_xor(mx, o, 64));
  if (!ln) red[wv] = mx;
  __syncthreads();
  mx = fmaxf(fmaxf(red[0], red[1]), fmaxf(red[2], red[3]));
  __syncthreads();
  float s = 0.f;
#pragma unroll
  for (int p = 0; p < 16; ++p) {
    v[p].x = __expf(v[p].x - mx);
    v[p].y = __expf(v[p].y - mx);
    v[p].z = __expf(v[p].z - mx);
    v[p].w = __expf(v[p].w - mx);
    s += v[p].x + v[p].y + v[p].z + v[p].w;
  }
  for (int o = 32; o; o >>= 1) s += __shfl_xor(s, o, 64);
  if (!ln) red[wv] = s;
  __syncthreads();
  const float inv = 1.f / (red[0] + red[1] + red[2] + red[3]);
  u16* op = expx + row * 16384;
#pragma unroll
  for (int p = 0; p < 16; ++p) {
    uint2 ow;
    ow.x = (u32)f2bf(v[p].x * inv) | ((u32)f2bf(v[p].y * inv) << 16);
    ow.y = (u32)f2bf(v[p].z * inv) | ((u32)f2bf(v[p].w * inv) << 16);
    *(uint2*)(op + tid * 4 + p * 1024) = ow;
  }
}

// ---------- pass 2: transpose xbf (bf16) into catT[b][n][512 + c]
__global__ __launch_bounds__(256) void transpose_x(const u16* __restrict__ xbf,
                                                   u16* __restrict__ catT) {
  __shared__ u16 t[32][33];
  const int b = blockIdx.z;
  const int c0 = blockIdx.y << 5, n0 = blockIdx.x << 5;
  const int tx = threadIdx.x & 31, ty = threadIdx.x >> 5;  // ty 0..7
  const u16* fb = xbf + (long long)b * 512 * 16384;
#pragma unroll
  for (int i = 0; i < 32; i += 8)
    t[ty + i][tx] = fb[(long long)(c0 + ty + i) * 16384 + n0 + tx];
  __syncthreads();
  u16* ob = catT + (long long)b * 16384 * 1024 + 512;
#pragma unroll
  for (int i = 0; i < 32; i += 8)
    ob[(long long)(n0 + ty + i) * 1024 + c0 + tx] = t[tx][ty + i];
}

// ---------- weight fp32 -> bf16 (7 tensors packed into one bf16 arena)
__global__ __launch_bounds__(256) void cvt_weights(
    const float* __restrict__ w0, const float* __restrict__ w1,
    const float* __restrict__ w2, const float* __restrict__ w3,
    const float* __restrict__ w4, const float* __restrict__ w5,
    const float* __restrict__ w6, u16* __restrict__ dst) {
  const long long i = (long long)blockIdx.x * 256 + threadIdx.x;  // < 1179648
  const float* s;
  long long off;
  if (i < 131072) { s = w0; off = 0; }            // wp1 256x512
  else if (i < 196608) { s = w1; off = 131072; }  // wp2 256x256
  else if (i < 327680) { s = w2; off = 196608; }  // wo1 256x512
  else if (i < 393216) { s = w3; off = 327680; }  // wo2 256x256
  else if (i < 524288) { s = w4; off = 393216; }  // wd  256x512
  else if (i < 655360) { s = w5; off = 524288; }  // wu  512x256
  else { s = w6; off = 655360; }                  // wout 512x1024
  dst[i] = f2bf(s[i - off]);
}

// ---------- big NT GEMM, 256x256 tile, BK=64, 512 threads (8 waves 2Mx4N),
// mfma 16x16x32 bf16, counted-vmcnt pipeline (T3+T4) with FINE INTERLEAVE:
//   - double-buffered 128KiB LDS, 2-K-tile prefetch depth; iteration kt
//     waits vmcnt(8) (ONLY tile kt's 8 loads — tile kt+1's stay in flight
//     across the barrier; never drains to 0 in the main loop).
//   - ds_read and MFMA interleaved per-mf ({2 ds_read -> 8 MFMA} x8) with
//     compiler-counted lgkmcnt — LDS pipe overlaps MFMA pipe (m196->m198
//     lever; the coarse read-all/drain/MFMA-all split serializes them).
//   - stage of tile kt+2 at the BOTTOM, after lgkmcnt(0)+barrier confirm
//     slot cur fully read.
//   - LDS chunk swizzle: 16B chunk c of row r at phys chunk c^(r&7);
//     global SOURCE pre-swizzled (gload_lds dest linear); read same XOR.
//   - s_setprio(1) around the read+MFMA region (T5).
// SPLITK = log2(#chunks) (0 = off): grid.z = batch<<SPLITK.
//   SPLITOUT=0: fp32 atomicAdd into C[batch]. SPLITOUT=1: plain fp32 store
//   into private chunk buffer C[bz] (reduce kernel sums later) — avoids
//   16-way cross-XCD atomic RMW contention.
// BIAS: 0 none, 1 per-row(M), 2 per-col(N'). ACT: relu. F32OUT: fp32 store.
template <int ACT, int BIAS, int SPLITK, int F32OUT, int SPLITOUT>
__global__ __launch_bounds__(512, 1) void gemm256_nt(
    const u16* __restrict__ A, long long sA, int lda,
    const u16* __restrict__ B, long long sB, int ldb,
    void* __restrict__ C, long long sC, int ldc,
    const float* __restrict__ bias, int K, int kchunk) {
  __shared__ __align__(16) u16 As[2][256 * 64];
  __shared__ __align__(16) u16 Bs[2][256 * 64];
  const int tid = threadIdx.x;
  const int wid = tid >> 6, ln = tid & 63;
  const int bz = blockIdx.z;
  const int batch = SPLITK ? (bz >> SPLITK) : bz;
  const int chunk = SPLITK ? (bz & ((1 << SPLITK) - 1)) : 0;
  const long long tm = (long long)blockIdx.y << 8;
  const long long tn = (long long)blockIdx.x << 8;
  // staging: lane ln of wave wid, stage s covers row s*64 + wid*8 + (ln>>3),
  // source chunk (ln&7)^(ln>>3)  (inverse of the read-side XOR).
  const int srow = wid * 8 + (ln >> 3);
  const int scl = ((ln & 7) ^ (ln >> 3)) << 3;  // u16 offset within row
  const long long koff = SPLITK ? (long long)chunk * kchunk : 0;
  const u16* Ab = A + (long long)batch * sA + koff + scl;
  const u16* Bb = B + (long long)batch * sB + koff + scl;
  const u16* rA[4];
  const u16* rB[4];
#pragma unroll
  for (int s = 0; s < 4; ++s) {
    rA[s] = Ab + (tm + s * 64 + srow) * (long long)lda;
    rB[s] = Bb + (tn + s * 64 + srow) * (long long)ldb;
  }
  auto stage = [&](int buf, int kk) {
#pragma unroll
    for (int s = 0; s < 4; ++s) {
      g2l16(&As[buf][s * 4096 + wid * 512], rA[s] + kk);
      g2l16(&Bs[buf][s * 4096 + wid * 512], rB[s] + kk);
    }
  };
  // fragment geometry
  const int fr = ln & 15, fq = ln >> 4;
  const int wm8 = wid >> 2;  // 0..1  (M half)
  const int wn8 = wid & 3;   // 0..3  (N quarter)
  const int arow = (wm8 * 128 + fr) * 64;  // u16 base of A frag rows
  const int brow = (wn8 * 64 + fr) * 64;
  const int ax = fr & 7;                     // row&7 for both A and B frags
  const int c0 = ((fq ^ ax) << 3);           // phys chunk offset, kslice 0
  const int c1 = c0 ^ 32;                    // kslice 1 (logical chunk +4)
  f32x4 acc[8][4] = {};
  const int nt = (SPLITK ? kchunk : K) >> 6;
  // prologue: stage tiles 0 and 1 (16 loads in flight); NO drain here.
  stage(0, 0);
  if (nt > 1) stage(1, 64);
  for (int kt = 0; kt < nt; ++kt) {
    const int cur = kt & 1;
    // wait for tile kt's loads only; tile kt+1's 8 remain in flight.
    if (kt + 1 < nt)
      asm volatile("s_waitcnt vmcnt(8)" ::: "memory");
    else
      asm volatile("s_waitcnt vmcnt(0)" ::: "memory");
    asm volatile("s_barrier" ::: "memory");  // all waves' tile-kt loads landed
    __builtin_amdgcn_s_setprio(1);
    // B fragments first, then per-mf {2 ds_read, 8 MFMA} — compiler emits
    // counted lgkmcnt so LDS reads overlap MFMA issue.
    s16x8 bfr[4][2];
#pragma unroll
    for (int nf = 0; nf < 4; ++nf) {
      bfr[nf][0] = *(const s16x8*)&Bs[cur][brow + nf * 1024 + c0];
      bfr[nf][1] = *(const s16x8*)&Bs[cur][brow + nf * 1024 + c1];
    }
#pragma unroll
    for (int mf = 0; mf < 8; ++mf) {
      s16x8 a0 = *(const s16x8*)&As[cur][arow + mf * 1024 + c0];
      s16x8 a1 = *(const s16x8*)&As[cur][arow + mf * 1024 + c1];
#pragma unroll
      for (int nf = 0; nf < 4; ++nf) {
        acc[mf][nf] = __builtin_amdgcn_mfma_f32_16x16x32_bf16(
            a0, bfr[nf][0], acc[mf][nf], 0, 0, 0);
        acc[mf][nf] = __builtin_amdgcn_mfma_f32_16x16x32_bf16(
            a1, bfr[nf][1], acc[mf][nf], 0, 0, 0);
      }
    }
    __builtin_amdgcn_s_setprio(0);
    // all ds_reads of slot cur retired (consumed by issued MFMAs); confirm
    // across waves, then reuse the slot for tile kt+2.
    asm volatile("s_waitcnt lgkmcnt(0)" ::: "memory");
    asm volatile("s_barrier" ::: "memory");
    if (kt + 2 < nt) stage(cur, (kt + 2) << 6);
  }
#pragma unroll
  for (int mf = 0; mf < 8; ++mf) {
    const long long gr0 = tm + wm8 * 128 + mf * 16 + fq * 4;
#pragma unroll
    for (int nf = 0; nf < 4; ++nf) {
      const long long gc = tn + wn8 * 64 + nf * 16 + fr;
      float bc = 0.f;
      if (BIAS == 2) bc = bias[gc];
#pragma unroll
      for (int t = 0; t < 4; ++t) {
        float v = acc[mf][nf][t];
        if (BIAS == 1) v += bias[gr0 + t];
        if (BIAS == 2) v += bc;
        if (ACT) v = fmaxf(v, 0.f);
        const long long cslot = (SPLITK && SPLITOUT) ? (long long)bz
                                                     : (long long)batch;
        const long long idx = cslot * sC + (gr0 + t) * ldc + gc;
        if (SPLITK && !SPLITOUT)
          atomicAdd((float*)C + idx, v);
        else if (F32OUT || SPLITOUT)
          ((float*)C)[idx] = v;
        else
          ((u16*)C)[idx] = f2bf(v);
      }
    }
  }
}

// ---------- small NT GEMM (128x128 tile, 2-buffer) — steps 4/5/6 only
template <int ACT, int BIAS, int AMODE, int BMODE, int F32OUT>
__global__ __launch_bounds__(256, 4) void gemm_nt(
    const void* __restrict__ Av, long long sA, int lda,
    const void* __restrict__ Bv, long long sB, int ldb,
    void* __restrict__ C, long long sC, int ldc,
    const float* __restrict__ bias, int K, int kchunk,
    const float2* __restrict__ stats, int statsStride) {
  __shared__ __align__(16) u16 Asm_[2][128 * 32];
  __shared__ __align__(16) u16 Bsm_[2][128 * 32];
  const int tid = threadIdx.x;
  const int wv = tid >> 6;
  const int ln = tid & 63;
  const int batch = blockIdx.z;
  const long long tm = (long long)blockIdx.y << 7;
  const long long tn = (long long)blockIdx.x << 7;
  const int lrow = ln >> 2;
  const int lcol = (((ln & 3) ^ ((ln >> 3) & 3)) << 3);
  const int w32 = wv << 5;
  const long long ar0 = tm + w32 + lrow, ar1 = ar0 + 16;
  const long long br0 = tn + w32 + lrow, br1 = br0 + 16;
  const long long koff = lcol;
  const u16* gau0 = (const u16*)Av + (long long)batch * sA + koff + ar0 * lda;
  const u16* gau1 = (const u16*)Av + (long long)batch * sA + koff + ar1 * lda;
  const u16* gbu0 = (const u16*)Bv + (long long)batch * sB + koff + br0 * ldb;
  const u16* gbu1 = (const u16*)Bv + (long long)batch * sB + koff + br1 * ldb;
  const int fr = ln & 15;
  const int fq = ln >> 4;
  const int wm = (wv >> 1) << 6;
  const int wn = (wv & 1) << 6;
  const int rx = (fq ^ ((fr >> 1) & 3)) << 3;
  f32x4 acc[4][4] = {};
  auto stage = [&](int bo, int kk) {
    g2l16(&Asm_[0][bo + w32 * 32], gau0 + kk);
    g2l16(&Asm_[0][bo + w32 * 32 + 512], gau1 + kk);
    g2l16(&Bsm_[0][bo + w32 * 32], gbu0 + kk);
    g2l16(&Bsm_[0][bo + w32 * 32 + 512], gbu1 + kk);
  };
  stage(0, 0);
  asm volatile("s_waitcnt vmcnt(0)" ::: "memory");
  asm volatile("s_barrier" ::: "memory");
  int cb = 0;
  for (int kk = 0; kk < K; kk += 32) {
    s16x8 af[4], bfr[4];
#pragma unroll
    for (int i = 0; i < 4; ++i)
      af[i] = *(const s16x8*)&Asm_[0][cb + (wm + i * 16 + fr) * 32 + rx];
#pragma unroll
    for (int j = 0; j < 4; ++j)
      bfr[j] = *(const s16x8*)&Bsm_[0][cb + (wn + j * 16 + fr) * 32 + rx];
    if (kk + 32 < K) stage(cb ^ 4096, kk + 32);
#pragma unroll
    for (int i = 0; i < 4; ++i)
#pragma unroll
      for (int j = 0; j < 4; ++j)
        acc[i][j] = __builtin_amdgcn_mfma_f32_16x16x32_bf16(
            af[i], bfr[j], acc[i][j], 0, 0, 0);
    __builtin_amdgcn_sched_barrier(0);
    asm volatile("s_waitcnt vmcnt(0) lgkmcnt(0)" ::: "memory");
    asm volatile("s_barrier" ::: "memory");
    cb ^= 4096;
  }
#pragma unroll
  for (int i = 0; i < 4; ++i) {
    const long long gr0 = tm + wm + i * 16 + fq * 4;
#pragma unroll
    for (int j = 0; j < 4; ++j) {
      const long long gc = tn + wn + j * 16 + fr;
      float bc = 0.f;
      if (BIAS == 2) bc = bias[gc];
#pragma unroll
      for (int t = 0; t < 4; ++t) {
        float v = acc[i][j][t];
        if (BIAS == 1) v += bias[gr0 + t];
        if (BIAS == 2) v += bc;
        if (ACT) v = fmaxf(v, 0.f);
        const long long idx = (long long)batch * sC + (gr0 + t) * ldc + gc;
        if (F32OUT)
          ((float*)C)[idx] = v;
        else
          ((u16*)C)[idx] = f2bf(v);
      }
    }
  }
}

// ---------- reduce 16 split-K fp32 chunk buffers -> bf16 contextT
// s = [4 batch][16 chunks][512*512] fp32, d = [4][512*512] bf16.
__global__ __launch_bounds__(256) void reduce16_bf16(const float* __restrict__ s,
                                                     u16* __restrict__ d) {
  const int i = blockIdx.x * 256 + threadIdx.x;  // float4 index, < 262144
  const int b = i >> 16, w = i & 65535;
  const float4* base = (const float4*)s + (long long)b * 16 * 65536 + w;
  float4 a = base[0];
#pragma unroll
  for (int c = 1; c < 16; ++c) {
    float4 t = base[(long long)c * 65536];
    a.x += t.x; a.y += t.y; a.z += t.z; a.w += t.w;
  }
  uint2 ow;
  ow.x = (u32)f2bf(a.x) | ((u32)f2bf(a.y) << 16);
  ow.y = (u32)f2bf(a.z) | ((u32)f2bf(a.w) << 16);
  *(uint2*)(d + (long long)i * 4) = ow;
}

// ---------- attention softmax: in-place bf16 row softmax over 512 cols,
// row pitch 1024 (sim lives in cols [0,512) of catT). scale = 1/16.
__global__ __launch_bounds__(256) void softmax_p(u16* __restrict__ P) {
  const int wv = threadIdx.x >> 6, ln = threadIdx.x & 63;
  const long long row = (long long)blockIdx.x * 4 + wv;
  u16* rp = P + row * 1024;
  uint4 r = *(const uint4*)(rp + ln * 8);
  u32 w[4] = {r.x, r.y, r.z, r.w};
  float v[8];
#pragma unroll
  for (int k = 0; k < 4; ++k) {
    v[2 * k] = __uint_as_float(w[k] << 16) * 0.0625f;
    v[2 * k + 1] = __uint_as_float(w[k] & 0xffff0000u) * 0.0625f;
  }
  float m = v[0];
#pragma unroll
  for (int t = 1; t < 8; ++t) m = fmaxf(m, v[t]);
  for (int o = 32; o; o >>= 1) m = fmaxf(m, __shfl_xor(m, o, 64));
  float e[8], s = 0.f;
#pragma unroll
  for (int t = 0; t < 8; ++t) {
    e[t] = __expf(v[t] - m);
    s += e[t];
  }
  for (int o = 32; o; o >>= 1) s += __shfl_xor(s, o, 64);
  const float inv = 1.f / s;
  u32 ow[4];
#pragma unroll
  for (int k = 0; k < 4; ++k)
    ow[k] = (u32)f2bf(e[2 * k] * inv) | ((u32)f2bf(e[2 * k + 1] * inv) << 16);
  *(uint4*)(rp + ln * 8) = make_uint4(ow[0], ow[1], ow[2], ow[3]);
}

// ---------- launch ----------
extern "C" void kernel_launch(void* const* d_in, const int* in_sizes, int n_in,
                              void* d_out, int out_size, void* d_ws, size_t ws_size,
                              hipStream_t stream) {
  const float* feat = (const float*)d_in[0];
  // d_in[1] = prob, dead.
  const float* wp1 = (const float*)d_in[2];
  const float* bp1 = (const float*)d_in[3];
  const float* wp2 = (const float*)d_in[4];
  const float* bp2 = (const float*)d_in[5];
  const float* wo1 = (const float*)d_in[6];
  const float* bo1 = (const float*)d_in[7];
  const float* wo2 = (const float*)d_in[8];
  const float* bo2 = (const float*)d_in[9];
  const float* wd = (const float*)d_in[10];
  const float* bd = (const float*)d_in[11];
  const float* wu = (const float*)d_in[12];
  const float* bu = (const float*)d_in[13];
  const float* wout = (const float*)d_in[14];
  const float* bout = (const float*)d_in[15];
  float* outp = (float*)d_out;
  char* ws = (char*)d_ws;

  // workspace layout (bytes):
  // [0, 128M)         catT [4][16384][1024] bf16: cols 0:512 = sim/P/ctxup,
  //                                               cols 512:1024 = xT
  // [128M, 192M)      expx [4][512][16384] bf16 (dead after step 3);
  //                   later q1T/ctxT at [128M,160M), qT at [160M,192M)
  // [192M, +2.25M)    wb (bf16 weight arena)
  // [196M..]          conT 2M, k1hT 1M, kT 1M, v 1M   (total 210763776)
  // d_out scratch: [0,64M) xbf bf16 (dead after step 3);
  //                [64M,128M) ctxChunks [4][16][512*512] fp32 split-K
  //                buffers (dead after reduce16). Step 13 overwrites d_out.
  u16* catT = (u16*)ws;
  u16* expx = (u16*)(ws + 134217728LL);
  u16* q1T = (u16*)(ws + 134217728LL);
  u16* ctxT = q1T;
  u16* qT = (u16*)(ws + 167772160LL);
  u16* wb = (u16*)(ws + 201326592LL);
  u16* conT = (u16*)(ws + 205520896LL);
  u16* k1hT = (u16*)(ws + 207618048LL);
  u16* kTm = (u16*)(ws + 208666624LL);
  u16* vm = (u16*)(ws + 209715200LL);
  if (ws_size < 210763776ULL) return;  // distinguishable failure: zero output
  u16* xbf = (u16*)d_out;
  float* ctxChunks = (float*)((char*)d_out + 67108864LL);
  u16* wp1b = wb + 0;
  u16* wp2b = wb + 131072;
  u16* wo1b = wb + 196608;
  u16* wo2b = wb + 327680;
  u16* wdb = wb + 393216;
  u16* wub = wb + 524288;
  u16* woutb = wb + 655360;

  // 1) row softmax of x -> expx bf16 + plain bf16 copy xbf (single feat read)
  row_softmax_bf16<<<2048, 256, 0, stream>>>(feat, expx, xbf);
  // 2) xT (bf16) into concat buffer, sourced from xbf
  transpose_x<<<dim3(512, 16, 4), 256, 0, stream>>>(xbf, catT);
  // 3) contextT[b][k'][c] = sum_n softmax(x)[k',n]*x[c,n]; 16-way split-K,
  //    private per-chunk fp32 buffers (no atomics), fused reduce after.
  gemm256_nt<0, 0, 4, 1, 1><<<dim3(2, 2, 64), 512, 0, stream>>>(
      expx, 8388608LL, 16384, xbf, 8388608LL, 16384, ctxChunks, 262144LL, 512,
      nullptr, 16384, 1024);
  reduce16_bf16<<<1024, 256, 0, stream>>>(ctxChunks, conT);
  // weights -> bf16 arena
  cvt_weights<<<4608, 256, 0, stream>>>(wp1, wp2, wo1, wo2, wd, wu, wout, wb);
  // 4) k1hT[k',d1] = relu(conT . wo1^T + bo1)
  gemm_nt<1, 2, 0, 0, 0><<<dim3(2, 4, 4), 256, 0, stream>>>(
      conT, 262144LL, 512, wo1b, 0LL, 512, k1hT, 131072LL, 256, bo1, 512, 0,
      nullptr, 0);
  // 5) kT[k',d2] = relu(k1hT . wo2^T + bo2)
  gemm_nt<1, 2, 0, 0, 0><<<dim3(2, 4, 4), 256, 0, stream>>>(
      k1hT, 131072LL, 256, wo2b, 0LL, 256, kTm, 131072LL, 256, bo2, 256, 0,
      nullptr, 0);
  // 6) v[d,k'] = relu(wd . conT^T + bd)
  gemm_nt<1, 1, 0, 0, 0><<<dim3(4, 2, 4), 256, 0, stream>>>(
      wdb, 0LL, 512, conT, 262144LL, 512, vm, 131072LL, 512, bd, 512, 0,
      nullptr, 0);
  // 7) q1T[n,d1] = relu(xT . wp1^T + bp1)
  gemm256_nt<1, 2, 0, 0, 0><<<dim3(1, 64, 4), 512, 0, stream>>>(
      catT + 512, 16777216LL, 1024, wp1b, 0LL, 512, q1T, 4194304LL, 256, bp1,
      512, 0);
  // 8) qT[n,d] = relu(q1T . wp2^T + bp2)
  gemm256_nt<1, 2, 0, 0, 0><<<dim3(1, 64, 4), 512, 0, stream>>>(
      q1T, 4194304LL, 256, wp2b, 0LL, 256, qT, 4194304LL, 256, bp2, 256, 0);
  // 9) sim[n,k'] = qT . kT^T -> catT cols 0:512
  gemm256_nt<0, 0, 0, 0, 0><<<dim3(2, 64, 4), 512, 0, stream>>>(
      qT, 4194304LL, 256, kTm, 131072LL, 256, catT, 16777216LL, 1024, nullptr,
      256, 0);
  // 10) P = softmax(sim/16) in place
  softmax_p<<<16384, 256, 0, stream>>>(catT);
  // 11) ctxT[n,d] = P . v^T
  gemm256_nt<0, 0, 0, 0, 0><<<dim3(1, 64, 4), 512, 0, stream>>>(
      catT, 16777216LL, 1024, vm, 131072LL, 512, ctxT, 4194304LL, 256, nullptr,
      512, 0);
  // 12) ctxupT[n,o] = relu(ctxT . wu^T + bu) -> catT cols 0:512
  gemm256_nt<1, 2, 0, 0, 0><<<dim3(2, 64, 4), 512, 0, stream>>>(
      ctxT, 4194304LL, 256, wub, 0LL, 256, catT, 16777216LL, 1024, bu, 256, 0);
  // 13) out[o,n] = relu(wout . concat(ctxup,x)^T + bout), fp32 output
  gemm256_nt<1, 1, 0, 1, 0><<<dim3(64, 2, 4), 512, 0, stream>>>(
      woutb, 0LL, 1024, catT, 16777216LL, 1024, outp, 8388608LL, 16384, bout,
      1024, 0);
}

// Round 9
// 638.734 us; speedup vs baseline: 1.0151x; 1.0151x over previous
//
#include <hip/hip_runtime.h>

typedef unsigned int u32;
typedef unsigned short u16;
typedef short s16x8 __attribute__((ext_vector_type(8)));
typedef float f32x4 __attribute__((ext_vector_type(4)));

// ---------- helpers ----------
__device__ __forceinline__ u16 f2bf(float f) {
  u32 u = __float_as_uint(f);
  u32 r = (u + 0x7fffu + ((u >> 16) & 1u)) >> 16;
  return (u16)r;
}

// async global->LDS, 16B per lane. LDS dest = wave-uniform base + lane*16.
__device__ __forceinline__ void g2l16(u16* lds, const u16* g) {
  __builtin_amdgcn_global_load_lds(
      (const __attribute__((address_space(1))) void*)g,
      (__attribute__((address_space(3))) void*)lds, 16, 0, 0);
}

// ---------- pass 1: per-row softmax over 16384 fp32 — SINGLE feat read.
__global__ __launch_bounds__(256) void row_softmax_bf16(
    const float* __restrict__ feat, u16* __restrict__ expx,
    u16* __restrict__ xbf) {
  const long long row = blockIdx.x;  // 0..2047
  const float* xp = feat + row * 16384;
  const int tid = threadIdx.x, wv = tid >> 6, ln = tid & 63;
  __shared__ float red[4];
  float4 v[16];
  float mx = -1e30f;
#pragma unroll
  for (int p = 0; p < 16; ++p) {
    v[p] = *(const float4*)(xp + tid * 4 + p * 1024);
    mx = fmaxf(mx, fmaxf(fmaxf(v[p].x, v[p].y), fmaxf(v[p].z, v[p].w)));
  }
  // bf16 copy of x (independent of stats) — store while regs are hot
  u16* bp = xbf + row * 16384;
#pragma unroll
  for (int p = 0; p < 16; ++p) {
    uint2 ow;
    ow.x = (u32)f2bf(v[p].x) | ((u32)f2bf(v[p].y) << 16);
    ow.y = (u32)f2bf(v[p].z) | ((u32)f2bf(v[p].w) << 16);
    *(uint2*)(bp + tid * 4 + p * 1024) = ow;
  }
  for (int o = 32; o; o >>= 1) mx = fmaxf(mx, __shfl_xor(mx, o, 64));
  if (!ln) red[wv] = mx;
  __syncthreads();
  mx = fmaxf(fmaxf(red[0], red[1]), fmaxf(red[2], red[3]));
  __syncthreads();
  float s = 0.f;
#pragma unroll
  for (int p = 0; p < 16; ++p) {
    v[p].x = __expf(v[p].x - mx);
    v[p].y = __expf(v[p].y - mx);
    v[p].z = __expf(v[p].z - mx);
    v[p].w = __expf(v[p].w - mx);
    s += v[p].x + v[p].y + v[p].z + v[p].w;
  }
  for (int o = 32; o; o >>= 1) s += __shfl_xor(s, o, 64);
  if (!ln) red[wv] = s;
  __syncthreads();
  const float inv = 1.f / (red[0] + red[1] + red[2] + red[3]);
  u16* op = expx + row * 16384;
#pragma unroll
  for (int p = 0; p < 16; ++p) {
    uint2 ow;
    ow.x = (u32)f2bf(v[p].x * inv) | ((u32)f2bf(v[p].y * inv) << 16);
    ow.y = (u32)f2bf(v[p].z * inv) | ((u32)f2bf(v[p].w * inv) << 16);
    *(uint2*)(op + tid * 4 + p * 1024) = ow;
  }
}

// ---------- pass 2: transpose xbf (bf16) into catT[b][n][512 + c]
__global__ __launch_bounds__(256) void transpose_x(const u16* __restrict__ xbf,
                                                   u16* __restrict__ catT) {
  __shared__ u16 t[32][33];
  const int b = blockIdx.z;
  const int c0 = blockIdx.y << 5, n0 = blockIdx.x << 5;
  const int tx = threadIdx.x & 31, ty = threadIdx.x >> 5;  // ty 0..7
  const u16* fb = xbf + (long long)b * 512 * 16384;
#pragma unroll
  for (int i = 0; i < 32; i += 8)
    t[ty + i][tx] = fb[(long long)(c0 + ty + i) * 16384 + n0 + tx];
  __syncthreads();
  u16* ob = catT + (long long)b * 16384 * 1024 + 512;
#pragma unroll
  for (int i = 0; i < 32; i += 8)
    ob[(long long)(n0 + ty + i) * 1024 + c0 + tx] = t[tx][ty + i];
}

// ---------- weight fp32 -> bf16 (7 tensors packed into one bf16 arena)
__global__ __launch_bounds__(256) void cvt_weights(
    const float* __restrict__ w0, const float* __restrict__ w1,
    const float* __restrict__ w2, const float* __restrict__ w3,
    const float* __restrict__ w4, const float* __restrict__ w5,
    const float* __restrict__ w6, u16* __restrict__ dst) {
  const long long i = (long long)blockIdx.x * 256 + threadIdx.x;  // < 1179648
  const float* s;
  long long off;
  if (i < 131072) { s = w0; off = 0; }            // wp1 256x512
  else if (i < 196608) { s = w1; off = 131072; }  // wp2 256x256
  else if (i < 327680) { s = w2; off = 196608; }  // wo1 256x512
  else if (i < 393216) { s = w3; off = 327680; }  // wo2 256x256
  else if (i < 524288) { s = w4; off = 393216; }  // wd  256x512
  else if (i < 655360) { s = w5; off = 524288; }  // wu  512x256
  else { s = w6; off = 655360; }                  // wout 512x1024
  dst[i] = f2bf(s[i - off]);
}

// ---------- big NT GEMM, 256x256 tile, BK=64, 512 threads (8 waves 2Mx4N),
// mfma 16x16x32 bf16 — m201-style 8-PHASE schedule (4 phases per K-tile):
//   phase q of tile kt: {ds_read one C-quadrant (mf-half x k-slice, 4-8
//   ds_read_b128) ; issue 2 staging global_load_lds ; s_barrier ;
//   lgkmcnt(0)+sched_barrier ; setprio(1) ; 16 MFMA ; setprio(0) ;
//   [vmcnt(4) at ph0/ph3 only] ; s_barrier}.
//   Staging of tile kt+1 is spread across tile kt's phases into regions
//   whose last reader retired >=1 barrier earlier:
//     ph0: (kt+1).B rows 0-127   (last read ph2 of kt-1)
//     ph1: (kt+1).B rows 128-255 (ditto)
//     ph2: (kt+1).A rows 64-127,192-255 (last read ph3 of kt-1)
//     ph3: (kt+2).A rows 0-63,128-191   (last read ph2 of kt)
//   vmcnt(4) (counted, NEVER 0 in the loop — T4): at each wait point the
//   4 newest issues are exactly the loads not yet needed. Prologue issues
//   t0 fully + t1.A02 (10 loads) to enter steady state.
//   LDS chunk swizzle: 16B chunk c of row r at phys c^(r&7); global SOURCE
//   pre-swizzled (gload_lds dest linear); read applies same XOR. 0 conflicts.
// SPLITK = log2(#chunks) (0 = off): grid.z = batch<<SPLITK.
//   SPLITOUT=1: plain fp32 store into private chunk buffer C[bz] (reduce
//   kernel sums later) — no cross-XCD atomic RMW.
// BIAS: 0 none, 1 per-row(M), 2 per-col(N'). ACT: relu. F32OUT: fp32 store.
template <int ACT, int BIAS, int SPLITK, int F32OUT, int SPLITOUT>
__global__ __launch_bounds__(512, 1) void gemm256_nt(
    const u16* __restrict__ A, long long sA, int lda,
    const u16* __restrict__ B, long long sB, int ldb,
    void* __restrict__ C, long long sC, int ldc,
    const float* __restrict__ bias, int K, int kchunk) {
  __shared__ __align__(16) u16 As[2][256 * 64];
  __shared__ __align__(16) u16 Bs[2][256 * 64];
  const int tid = threadIdx.x;
  const int wid = tid >> 6, ln = tid & 63;
  const int bz = blockIdx.z;
  const int batch = SPLITK ? (bz >> SPLITK) : bz;
  const int chunk = SPLITK ? (bz & ((1 << SPLITK) - 1)) : 0;
  const long long tm = (long long)blockIdx.y << 8;
  const long long tn = (long long)blockIdx.x << 8;
  // staging: call s covers rows s*64 + wid*8 + (ln>>3), 8 chunks per row;
  // source chunk (ln&7)^(ln>>3) = inverse of the read-side XOR.
  const int srow = wid * 8 + (ln >> 3);
  const int scl = ((ln & 7) ^ (ln >> 3)) << 3;
  const long long koff = SPLITK ? (long long)chunk * kchunk : 0;
  const u16* Ab = A + (long long)batch * sA + koff + scl;
  const u16* Bb = B + (long long)batch * sB + koff + scl;
  const u16* rA[4];
  const u16* rB[4];
#pragma unroll
  for (int s = 0; s < 4; ++s) {
    rA[s] = Ab + (tm + s * 64 + srow) * (long long)lda;
    rB[s] = Bb + (tn + s * 64 + srow) * (long long)ldb;
  }
  const int dst = wid * 512;
  // A pair pr: calls {pr, pr+2} (rows pr*64..  and (pr+2)*64.. : the two
  // 64-row blocks read by mf0-3 (pr=0) / mf4-7 (pr=1) across both M-halves).
  auto sA2 = [&](int buf, int kk, int pr) {
    g2l16(&As[buf][pr * 4096 + dst], rA[pr] + kk);
    g2l16(&As[buf][(pr + 2) * 4096 + dst], rA[pr + 2] + kk);
  };
  // B pair pr: calls {2pr, 2pr+1} (rows 0-127 / 128-255).
  auto sB2 = [&](int buf, int kk, int pr) {
    g2l16(&Bs[buf][(2 * pr) * 4096 + dst], rB[2 * pr] + kk);
    g2l16(&Bs[buf][(2 * pr + 1) * 4096 + dst], rB[2 * pr + 1] + kk);
  };
  // fragment geometry
  const int fr = ln & 15, fq = ln >> 4;
  const int wm8 = wid >> 2;  // 0..1  (M half)
  const int wn8 = wid & 3;   // 0..3  (N quarter)
  const int arow = (wm8 * 128 + fr) * 64;
  const int brow = (wn8 * 64 + fr) * 64;
  const int ax = fr & 7;
  const int c0 = ((fq ^ ax) << 3);  // phys chunk offset, k-slice 0
  const int c1 = c0 ^ 32;           // k-slice 1
  f32x4 acc[8][4] = {};
  const int nt = (SPLITK ? kchunk : K) >> 6;
  // prologue (steady-state issue order): t0.A02, t0.B01, t0.B23, t0.A13,
  // t1.A02 — then counted wait covers exactly what ph0(0) reads.
  sA2(0, 0, 0);
  sB2(0, 0, 0);
  sB2(0, 0, 1);
  sA2(0, 0, 1);
  if (nt > 1) sA2(1, 64, 0);
  asm volatile("s_waitcnt vmcnt(4)" ::: "memory");
  asm volatile("s_barrier" ::: "memory");
  s16x8 bfr[4][2], af[4];
  for (int kt = 0; kt < nt; ++kt) {
    const int cur = kt & 1, nxt = cur ^ 1;
    const int k1 = (kt + 1) << 6, k2 = (kt + 2) << 6;
    // ---- phase 0: quadrant (mf0-3, ks0) ----
#pragma unroll
    for (int nf = 0; nf < 4; ++nf)
      bfr[nf][0] = *(const s16x8*)&Bs[cur][brow + nf * 1024 + c0];
#pragma unroll
    for (int mf = 0; mf < 4; ++mf)
      af[mf] = *(const s16x8*)&As[cur][arow + mf * 1024 + c0];
    if (kt + 1 < nt) sB2(nxt, k1, 0);
    asm volatile("s_barrier" ::: "memory");
    asm volatile("s_waitcnt lgkmcnt(0)" ::: "memory");
    __builtin_amdgcn_sched_barrier(0);
    __builtin_amdgcn_s_setprio(1);
#pragma unroll
    for (int mf = 0; mf < 4; ++mf)
#pragma unroll
      for (int nf = 0; nf < 4; ++nf)
        acc[mf][nf] = __builtin_amdgcn_mfma_f32_16x16x32_bf16(
            af[mf], bfr[nf][0], acc[mf][nf], 0, 0, 0);
    __builtin_amdgcn_s_setprio(0);
    asm volatile("s_waitcnt vmcnt(4)" ::: "memory");  // covers ph1's A13
    asm volatile("s_barrier" ::: "memory");
    // ---- phase 1: quadrant (mf4-7, ks0) ----
#pragma unroll
    for (int mf = 0; mf < 4; ++mf)
      af[mf] = *(const s16x8*)&As[cur][arow + (mf + 4) * 1024 + c0];
    if (kt + 1 < nt) sB2(nxt, k1, 1);
    asm volatile("s_barrier" ::: "memory");
    asm volatile("s_waitcnt lgkmcnt(0)" ::: "memory");
    __builtin_amdgcn_sched_barrier(0);
    __builtin_amdgcn_s_setprio(1);
#pragma unroll
    for (int mf = 0; mf < 4; ++mf)
#pragma unroll
      for (int nf = 0; nf < 4; ++nf)
        acc[mf + 4][nf] = __builtin_amdgcn_mfma_f32_16x16x32_bf16(
            af[mf], bfr[nf][0], acc[mf + 4][nf], 0, 0, 0);
    __builtin_amdgcn_s_setprio(0);
    asm volatile("s_barrier" ::: "memory");
    // ---- phase 2: quadrant (mf0-3, ks1) ----
#pragma unroll
    for (int nf = 0; nf < 4; ++nf)
      bfr[nf][1] = *(const s16x8*)&Bs[cur][brow + nf * 1024 + c1];
#pragma unroll
    for (int mf = 0; mf < 4; ++mf)
      af[mf] = *(const s16x8*)&As[cur][arow + mf * 1024 + c1];
    if (kt + 1 < nt) sA2(nxt, k1, 1);
    asm volatile("s_barrier" ::: "memory");
    asm volatile("s_waitcnt lgkmcnt(0)" ::: "memory");
    __builtin_amdgcn_sched_barrier(0);
    __builtin_amdgcn_s_setprio(1);
#pragma unroll
    for (int mf = 0; mf < 4; ++mf)
#pragma unroll
      for (int nf = 0; nf < 4; ++nf)
        acc[mf][nf] = __builtin_amdgcn_mfma_f32_16x16x32_bf16(
            af[mf], bfr[nf][1], acc[mf][nf], 0, 0, 0);
    __builtin_amdgcn_s_setprio(0);
    asm volatile("s_barrier" ::: "memory");
    // ---- phase 3: quadrant (mf4-7, ks1) ----
#pragma unroll
    for (int mf = 0; mf < 4; ++mf)
      af[mf] = *(const s16x8*)&As[cur][arow + (mf + 4) * 1024 + c1];
    if (kt + 2 < nt) sA2(cur, k2, 0);
    asm volatile("s_barrier" ::: "memory");
    asm volatile("s_waitcnt lgkmcnt(0)" ::: "memory");
    __builtin_amdgcn_sched_barrier(0);
    __builtin_amdgcn_s_setprio(1);
#pragma unroll
    for (int mf = 0; mf < 4; ++mf)
#pragma unroll
      for (int nf = 0; nf < 4; ++nf)
        acc[mf + 4][nf] = __builtin_amdgcn_mfma_f32_16x16x32_bf16(
            af[mf], bfr[nf][1], acc[mf + 4][nf], 0, 0, 0);
    __builtin_amdgcn_s_setprio(0);
    asm volatile("s_waitcnt vmcnt(4)" ::: "memory");  // covers next ph0
    asm volatile("s_barrier" ::: "memory");
  }
#pragma unroll
  for (int mf = 0; mf < 8; ++mf) {
    const long long gr0 = tm + wm8 * 128 + mf * 16 + fq * 4;
#pragma unroll
    for (int nf = 0; nf < 4; ++nf) {
      const long long gc = tn + wn8 * 64 + nf * 16 + fr;
      float bc = 0.f;
      if (BIAS == 2) bc = bias[gc];
#pragma unroll
      for (int t = 0; t < 4; ++t) {
        float v = acc[mf][nf][t];
        if (BIAS == 1) v += bias[gr0 + t];
        if (BIAS == 2) v += bc;
        if (ACT) v = fmaxf(v, 0.f);
        const long long cslot = (SPLITK && SPLITOUT) ? (long long)bz
                                                     : (long long)batch;
        const long long idx = cslot * sC + (gr0 + t) * ldc + gc;
        if (SPLITK && !SPLITOUT)
          atomicAdd((float*)C + idx, v);
        else if (F32OUT || SPLITOUT)
          ((float*)C)[idx] = v;
        else
          ((u16*)C)[idx] = f2bf(v);
      }
    }
  }
}

// ---------- small NT GEMM (128x128 tile, 2-buffer) — steps 4/5/6 only
template <int ACT, int BIAS, int AMODE, int BMODE, int F32OUT>
__global__ __launch_bounds__(256, 4) void gemm_nt(
    const void* __restrict__ Av, long long sA, int lda,
    const void* __restrict__ Bv, long long sB, int ldb,
    void* __restrict__ C, long long sC, int ldc,
    const float* __restrict__ bias, int K, int kchunk,
    const float2* __restrict__ stats, int statsStride) {
  __shared__ __align__(16) u16 Asm_[2][128 * 32];
  __shared__ __align__(16) u16 Bsm_[2][128 * 32];
  const int tid = threadIdx.x;
  const int wv = tid >> 6;
  const int ln = tid & 63;
  const int batch = blockIdx.z;
  const long long tm = (long long)blockIdx.y << 7;
  const long long tn = (long long)blockIdx.x << 7;
  const int lrow = ln >> 2;
  const int lcol = (((ln & 3) ^ ((ln >> 3) & 3)) << 3);
  const int w32 = wv << 5;
  const long long ar0 = tm + w32 + lrow, ar1 = ar0 + 16;
  const long long br0 = tn + w32 + lrow, br1 = br0 + 16;
  const long long koff = lcol;
  const u16* gau0 = (const u16*)Av + (long long)batch * sA + koff + ar0 * lda;
  const u16* gau1 = (const u16*)Av + (long long)batch * sA + koff + ar1 * lda;
  const u16* gbu0 = (const u16*)Bv + (long long)batch * sB + koff + br0 * ldb;
  const u16* gbu1 = (const u16*)Bv + (long long)batch * sB + koff + br1 * ldb;
  const int fr = ln & 15;
  const int fq = ln >> 4;
  const int wm = (wv >> 1) << 6;
  const int wn = (wv & 1) << 6;
  const int rx = (fq ^ ((fr >> 1) & 3)) << 3;
  f32x4 acc[4][4] = {};
  auto stage = [&](int bo, int kk) {
    g2l16(&Asm_[0][bo + w32 * 32], gau0 + kk);
    g2l16(&Asm_[0][bo + w32 * 32 + 512], gau1 + kk);
    g2l16(&Bsm_[0][bo + w32 * 32], gbu0 + kk);
    g2l16(&Bsm_[0][bo + w32 * 32 + 512], gbu1 + kk);
  };
  stage(0, 0);
  asm volatile("s_waitcnt vmcnt(0)" ::: "memory");
  asm volatile("s_barrier" ::: "memory");
  int cb = 0;
  for (int kk = 0; kk < K; kk += 32) {
    s16x8 af[4], bfr[4];
#pragma unroll
    for (int i = 0; i < 4; ++i)
      af[i] = *(const s16x8*)&Asm_[0][cb + (wm + i * 16 + fr) * 32 + rx];
#pragma unroll
    for (int j = 0; j < 4; ++j)
      bfr[j] = *(const s16x8*)&Bsm_[0][cb + (wn + j * 16 + fr) * 32 + rx];
    if (kk + 32 < K) stage(cb ^ 4096, kk + 32);
#pragma unroll
    for (int i = 0; i < 4; ++i)
#pragma unroll
      for (int j = 0; j < 4; ++j)
        acc[i][j] = __builtin_amdgcn_mfma_f32_16x16x32_bf16(
            af[i], bfr[j], acc[i][j], 0, 0, 0);
    __builtin_amdgcn_sched_barrier(0);
    asm volatile("s_waitcnt vmcnt(0) lgkmcnt(0)" ::: "memory");
    asm volatile("s_barrier" ::: "memory");
    cb ^= 4096;
  }
#pragma unroll
  for (int i = 0; i < 4; ++i) {
    const long long gr0 = tm + wm + i * 16 + fq * 4;
#pragma unroll
    for (int j = 0; j < 4; ++j) {
      const long long gc = tn + wn + j * 16 + fr;
      float bc = 0.f;
      if (BIAS == 2) bc = bias[gc];
#pragma unroll
      for (int t = 0; t < 4; ++t) {
        float v = acc[i][j][t];
        if (BIAS == 1) v += bias[gr0 + t];
        if (BIAS == 2) v += bc;
        if (ACT) v = fmaxf(v, 0.f);
        const long long idx = (long long)batch * sC + (gr0 + t) * ldc + gc;
        if (F32OUT)
          ((float*)C)[idx] = v;
        else
          ((u16*)C)[idx] = f2bf(v);
      }
    }
  }
}

// ---------- reduce 16 split-K fp32 chunk buffers -> bf16 contextT
// s = [4 batch][16 chunks][512*512] fp32, d = [4][512*512] bf16.
__global__ __launch_bounds__(256) void reduce16_bf16(const float* __restrict__ s,
                                                     u16* __restrict__ d) {
  const int i = blockIdx.x * 256 + threadIdx.x;  // float4 index, < 262144
  const int b = i >> 16, w = i & 65535;
  const float4* base = (const float4*)s + (long long)b * 16 * 65536 + w;
  float4 a = base[0];
#pragma unroll
  for (int c = 1; c < 16; ++c) {
    float4 t = base[(long long)c * 65536];
    a.x += t.x; a.y += t.y; a.z += t.z; a.w += t.w;
  }
  uint2 ow;
  ow.x = (u32)f2bf(a.x) | ((u32)f2bf(a.y) << 16);
  ow.y = (u32)f2bf(a.z) | ((u32)f2bf(a.w) << 16);
  *(uint2*)(d + (long long)i * 4) = ow;
}

// ---------- attention softmax: in-place bf16 row softmax over 512 cols,
// row pitch 1024 (sim lives in cols [0,512) of catT). scale = 1/16.
__global__ __launch_bounds__(256) void softmax_p(u16* __restrict__ P) {
  const int wv = threadIdx.x >> 6, ln = threadIdx.x & 63;
  const long long row = (long long)blockIdx.x * 4 + wv;
  u16* rp = P + row * 1024;
  uint4 r = *(const uint4*)(rp + ln * 8);
  u32 w[4] = {r.x, r.y, r.z, r.w};
  float v[8];
#pragma unroll
  for (int k = 0; k < 4; ++k) {
    v[2 * k] = __uint_as_float(w[k] << 16) * 0.0625f;
    v[2 * k + 1] = __uint_as_float(w[k] & 0xffff0000u) * 0.0625f;
  }
  float m = v[0];
#pragma unroll
  for (int t = 1; t < 8; ++t) m = fmaxf(m, v[t]);
  for (int o = 32; o; o >>= 1) m = fmaxf(m, __shfl_xor(m, o, 64));
  float e[8], s = 0.f;
#pragma unroll
  for (int t = 0; t < 8; ++t) {
    e[t] = __expf(v[t] - m);
    s += e[t];
  }
  for (int o = 32; o; o >>= 1) s += __shfl_xor(s, o, 64);
  const float inv = 1.f / s;
  u32 ow[4];
#pragma unroll
  for (int k = 0; k < 4; ++k)
    ow[k] = (u32)f2bf(e[2 * k] * inv) | ((u32)f2bf(e[2 * k + 1] * inv) << 16);
  *(uint4*)(rp + ln * 8) = make_uint4(ow[0], ow[1], ow[2], ow[3]);
}

// ---------- launch ----------
extern "C" void kernel_launch(void* const* d_in, const int* in_sizes, int n_in,
                              void* d_out, int out_size, void* d_ws, size_t ws_size,
                              hipStream_t stream) {
  const float* feat = (const float*)d_in[0];
  // d_in[1] = prob, dead.
  const float* wp1 = (const float*)d_in[2];
  const float* bp1 = (const float*)d_in[3];
  const float* wp2 = (const float*)d_in[4];
  const float* bp2 = (const float*)d_in[5];
  const float* wo1 = (const float*)d_in[6];
  const float* bo1 = (const float*)d_in[7];
  const float* wo2 = (const float*)d_in[8];
  const float* bo2 = (const float*)d_in[9];
  const float* wd = (const float*)d_in[10];
  const float* bd = (const float*)d_in[11];
  const float* wu = (const float*)d_in[12];
  const float* bu = (const float*)d_in[13];
  const float* wout = (const float*)d_in[14];
  const float* bout = (const float*)d_in[15];
  float* outp = (float*)d_out;
  char* ws = (char*)d_ws;

  // workspace layout (bytes):
  // [0, 128M)         catT [4][16384][1024] bf16: cols 0:512 = sim/P/ctxup,
  //                                               cols 512:1024 = xT
  // [128M, 192M)      expx [4][512][16384] bf16 (dead after step 3);
  //                   later q1T/ctxT at [128M,160M), qT at [160M,192M)
  // [192M, +2.25M)    wb (bf16 weight arena)
  // [196M..]          conT 2M, k1hT 1M, kT 1M, v 1M   (total 210763776)
  // d_out scratch: [0,64M) xbf bf16 (dead after step 3);
  //                [64M,128M) ctxChunks [4][16][512*512] fp32 split-K
  //                buffers (dead after reduce16). Step 13 overwrites d_out.
  u16* catT = (u16*)ws;
  u16* expx = (u16*)(ws + 134217728LL);
  u16* q1T = (u16*)(ws + 134217728LL);
  u16* ctxT = q1T;
  u16* qT = (u16*)(ws + 167772160LL);
  u16* wb = (u16*)(ws + 201326592LL);
  u16* conT = (u16*)(ws + 205520896LL);
  u16* k1hT = (u16*)(ws + 207618048LL);
  u16* kTm = (u16*)(ws + 208666624LL);
  u16* vm = (u16*)(ws + 209715200LL);
  if (ws_size < 210763776ULL) return;  // distinguishable failure: zero output
  u16* xbf = (u16*)d_out;
  float* ctxChunks = (float*)((char*)d_out + 67108864LL);
  u16* wp1b = wb + 0;
  u16* wp2b = wb + 131072;
  u16* wo1b = wb + 196608;
  u16* wo2b = wb + 327680;
  u16* wdb = wb + 393216;
  u16* wub = wb + 524288;
  u16* woutb = wb + 655360;

  // 1) row softmax of x -> expx bf16 + plain bf16 copy xbf (single feat read)
  row_softmax_bf16<<<2048, 256, 0, stream>>>(feat, expx, xbf);
  // 2) xT (bf16) into concat buffer, sourced from xbf
  transpose_x<<<dim3(512, 16, 4), 256, 0, stream>>>(xbf, catT);
  // 3) contextT[b][k'][c] = sum_n softmax(x)[k',n]*x[c,n]; 16-way split-K,
  //    private per-chunk fp32 buffers (no atomics), fused reduce after.
  gemm256_nt<0, 0, 4, 1, 1><<<dim3(2, 2, 64), 512, 0, stream>>>(
      expx, 8388608LL, 16384, xbf, 8388608LL, 16384, ctxChunks, 262144LL, 512,
      nullptr, 16384, 1024);
  reduce16_bf16<<<1024, 256, 0, stream>>>(ctxChunks, conT);
  // weights -> bf16 arena
  cvt_weights<<<4608, 256, 0, stream>>>(wp1, wp2, wo1, wo2, wd, wu, wout, wb);
  // 4) k1hT[k',d1] = relu(conT . wo1^T + bo1)
  gemm_nt<1, 2, 0, 0, 0><<<dim3(2, 4, 4), 256, 0, stream>>>(
      conT, 262144LL, 512, wo1b, 0LL, 512, k1hT, 131072LL, 256, bo1, 512, 0,
      nullptr, 0);
  // 5) kT[k',d2] = relu(k1hT . wo2^T + bo2)
  gemm_nt<1, 2, 0, 0, 0><<<dim3(2, 4, 4), 256, 0, stream>>>(
      k1hT, 131072LL, 256, wo2b, 0LL, 256, kTm, 131072LL, 256, bo2, 256, 0,
      nullptr, 0);
  // 6) v[d,k'] = relu(wd . conT^T + bd)
  gemm_nt<1, 1, 0, 0, 0><<<dim3(4, 2, 4), 256, 0, stream>>>(
      wdb, 0LL, 512, conT, 262144LL, 512, vm, 131072LL, 512, bd, 512, 0,
      nullptr, 0);
  // 7) q1T[n,d1] = relu(xT . wp1^T + bp1)
  gemm256_nt<1, 2, 0, 0, 0><<<dim3(1, 64, 4), 512, 0, stream>>>(
      catT + 512, 16777216LL, 1024, wp1b, 0LL, 512, q1T, 4194304LL, 256, bp1,
      512, 0);
  // 8) qT[n,d] = relu(q1T . wp2^T + bp2)
  gemm256_nt<1, 2, 0, 0, 0><<<dim3(1, 64, 4), 512, 0, stream>>>(
      q1T, 4194304LL, 256, wp2b, 0LL, 256, qT, 4194304LL, 256, bp2, 256, 0);
  // 9) sim[n,k'] = qT . kT^T -> catT cols 0:512
  gemm256_nt<0, 0, 0, 0, 0><<<dim3(2, 64, 4), 512, 0, stream>>>(
      qT, 4194304LL, 256, kTm, 131072LL, 256, catT, 16777216LL, 1024, nullptr,
      256, 0);
  // 10) P = softmax(sim/16) in place
  softmax_p<<<16384, 256, 0, stream>>>(catT);
  // 11) ctxT[n,d] = P . v^T
  gemm256_nt<0, 0, 0, 0, 0><<<dim3(1, 64, 4), 512, 0, stream>>>(
      catT, 16777216LL, 1024, vm, 131072LL, 512, ctxT, 4194304LL, 256, nullptr,
      512, 0);
  // 12) ctxupT[n,o] = relu(ctxT . wu^T + bu) -> catT cols 0:512
  gemm256_nt<1, 2, 0, 0, 0><<<dim3(2, 64, 4), 512, 0, stream>>>(
      ctxT, 4194304LL, 256, wub, 0LL, 256, catT, 16777216LL, 1024, bu, 256, 0);
  // 13) out[o,n] = relu(wout . concat(ctxup,x)^T + bout), fp32 output
  gemm256_nt<1, 1, 0, 1, 0><<<dim3(64, 2, 4), 512, 0, stream>>>(
      woutb, 0LL, 1024, catT, 16777216LL, 1024, outp, 8388608LL, 16384, bout,
      1024, 0);
}